// Round 12
// baseline (285.157 us; speedup 1.0000x reference)
//
#include <hip/hip_runtime.h>
#include <hip/hip_bf16.h>
#include <stdint.h>

#define B_     2
#define N_     2048
#define QD_    1024
#define H_     16
#define DH_    64
#define INNER_ 1024
#define SCALE_ 0.125f

typedef unsigned short u16;
typedef __attribute__((ext_vector_type(8))) short bf16x8;   // 8 bf16 = 4 VGPRs
typedef __attribute__((ext_vector_type(4))) float f32x4;    // MFMA C/D frag
typedef __attribute__((ext_vector_type(4))) unsigned short u16x4;
typedef __attribute__((ext_vector_type(8))) unsigned short u16x8;

// ---- bf16 helpers (RNE) ----
__device__ inline u16 f2bf(float f) {
    union { float f; uint32_t u; } c; c.f = f;
    uint32_t r = c.u + 0x7FFFu + ((c.u >> 16) & 1u);
    return (u16)(r >> 16);
}
__device__ inline float bf2f(u16 s) {
    union { uint32_t u; float f; } c; c.u = ((uint32_t)s) << 16;
    return c.f;
}
__device__ inline void split2(float v, u16 &h, u16 &l) {
    u16 hs = f2bf(v);
    h = hs;
    l = f2bf(v - bf2f(hs));
}
// packed RNE f32x2 -> bf16x2 (v_cvt_pk_bf16_f32 on gfx950)
__device__ inline void pack2(float a, float b, u16 &lo, u16 &hi) {
    float2 f; f.x = a; f.y = b;
    union { __hip_bfloat162 v; u16 u[2]; } c;
    c.v = __float22bfloat162_rn(f);
    lo = c.u[0]; hi = c.u[1];
}

// ---- prep: split_x (blocks 0..4095) + W transposes (blocks 4096..8191) ----
__global__ __launch_bounds__(256) void prep_kernel(
    const float* __restrict__ x, u16* __restrict__ xh, u16* __restrict__ xl,
    const float* __restrict__ Wq, const float* __restrict__ Wkv, const float* __restrict__ Wo,
    u16* __restrict__ wTh, u16* __restrict__ wTl,
    u16* __restrict__ woTh, u16* __restrict__ woTl)
{
    __shared__ float t[32][33];
    const int blk = blockIdx.x, tid = threadIdx.x;
    if (blk < 4096) {
        int idx = blk * 256 + tid;
        float4 v = ((const float4*)x)[idx];
        u16x4 hv, lv; u16 h, l;
        split2(v.x, h, l); hv.x = h; lv.x = l;
        split2(v.y, h, l); hv.y = h; lv.y = l;
        split2(v.z, h, l); hv.z = h; lv.z = l;
        split2(v.w, h, l); hv.w = h; lv.w = l;
        ((u16x4*)xh)[idx] = hv;
        ((u16x4*)xl)[idx] = lv;
        return;
    }
    int local = blk - 4096;
    const float* src; u16 *dhi, *dlo; int C, bx, by;
    if (local < 1024)      { src = Wq;  dhi = wTh;                dlo = wTl;                C = 1024; by = local >> 5; bx = local & 31; }
    else if (local < 3072) { int l2 = local - 1024; src = Wkv; dhi = wTh + 1024 * 1024; dlo = wTl + 1024 * 1024; C = 2048; by = l2 >> 6; bx = l2 & 63; }
    else                   { int l2 = local - 3072; src = Wo;  dhi = woTh;               dlo = woTl;               C = 1024; by = l2 >> 5; bx = l2 & 31; }
    const int x0 = bx * 32, y0 = by * 32;
    const int tx = tid & 31, ty = tid >> 5;
    for (int yy = ty; yy < 32; yy += 8)
        t[yy][tx] = src[(size_t)(y0 + yy) * C + x0 + tx];
    __syncthreads();
    for (int i = ty; i < 32; i += 8) {
        float v = t[tx][i];
        u16 h, l; split2(v, h, l);
        size_t o = (size_t)(x0 + i) * 1024 + y0 + tx;
        dhi[o] = h; dlo[o] = l;
    }
}

// ---- stage 1: GEMM x @ [Wq|Wkv] + co-scheduled bias swizzle.
// Q cols (bx<8): 2-term; KV cols: 1-term.
// Bias output layout (u16): bsw[((((b*32+qt)*16 + jt)*4 + wv)*64 + lane)*32
//                               + n*16 + m*4 + qr]
//   where key = jt*128 + wv*32 + n*16 + (lane&15), q = qt*64 + m*16 + (lane>>4)*4 + qr.
// Each attn lane then reads its jtile bias as 64B contiguous (coalesced).
__global__ __launch_bounds__(256) void gemm_qkv_bias(
    int mode,
    const u16* __restrict__ Ah, const u16* __restrict__ Al,
    const u16* __restrict__ Bh,
    u16* __restrict__ qh,
    u16* __restrict__ kb, u16* __restrict__ vT,
    const float* __restrict__ bias, const int* __restrict__ mask,
    u16* __restrict__ bsw)
{
    __shared__ __align__(16) char smem[24576];
    const int tid = threadIdx.x;

    int gid = -1, bid = -1;
    if (mode == 1) {
        if (blockIdx.x < 768) gid = blockIdx.x; else bid = blockIdx.x - 768;
    } else if (mode == 0) gid = blockIdx.x;
    else bid = blockIdx.x;

    if (bid >= 0) {
        float (*t)[65] = (float(*)[65])smem;   // 64x65 fp32 = 16640 <= 24576
        const int b = bid >> 10, rest = bid & 1023;
        const int k0 = (rest & 31) * 64, q0 = (rest >> 5) * 64;
#pragma unroll
        for (int it = 0; it < 16; it++) {
            int idx = it * 256 + tid;
            int qq = idx >> 6, kk = idx & 63;
            t[qq][kk] = bias[((size_t)b * N_ + q0 + qq) * N_ + k0 + kk];
        }
        __syncthreads();
        const u16 NEG = f2bf(-1e30f);
        const int qt = q0 >> 6, jt = k0 >> 7, w0 = (k0 >> 5) & 3;
        const int p = tid >> 1, hf = tid & 1;          // p: (wv,lane) pair; hf = n
        const int wv = w0 + (p >> 6), lane = p & 63;
        const int quad = lane >> 4, l16 = lane & 15;
        const int kk = (p >> 6) * 32 + hf * 16 + l16;  // key - k0, in 0..63
        const int mok = mask[b * N_ + k0 + kk];
        u16x8 o0, o1;
#pragma unroll
        for (int i = 0; i < 8; i++) {
            int m = i >> 2, qr = i & 3;
            int qq = m * 16 + quad * 4 + qr;
            o0[i] = mok ? f2bf(t[qq][kk]) : NEG;
        }
#pragma unroll
        for (int i = 0; i < 8; i++) {
            int m = 2 + (i >> 2), qr = i & 3;
            int qq = m * 16 + quad * 4 + qr;
            o1[i] = mok ? f2bf(t[qq][kk]) : NEG;
        }
        size_t ob = ((((size_t)b * 32 + qt) * 16 + jt) * 4 + wv) * 2048
                    + (size_t)lane * 32 + hf * 16;
        *(u16x8*)&bsw[ob]     = o0;
        *(u16x8*)&bsw[ob + 8] = o1;
        return;
    }

    u16* sAh = (u16*)smem;
    u16* sAl = (u16*)(smem + 8192);
    u16* sBh = (u16*)(smem + 16384);
    const int wave = tid >> 6, lane = tid & 63;
    const int quad = lane >> 4, l16 = lane & 15;
    const int wm = wave >> 1, wn = wave & 1;
    const int bx = gid % 24, by = gid / 24;
    const int bm = by * 128, bn = bx * 128;
    const bool comp = (bx < 8);

    f32x4 acc[4][4];
#pragma unroll
    for (int i = 0; i < 4; i++)
#pragma unroll
        for (int j = 0; j < 4; j++) acc[i][j] = (f32x4){0.f, 0.f, 0.f, 0.f};

    const int row0 = tid >> 2, g4 = tid & 3;
    const int r1 = row0, r2 = row0 + 64;
    const int gc1 = (g4 ^ (r1 & 3)) * 8, gc2 = (g4 ^ (r2 & 3)) * 8;
    const size_t a1 = (size_t)(bm + r1) * 1024 + gc1, a2 = (size_t)(bm + r2) * 1024 + gc2;
    const size_t b1 = (size_t)(bn + r1) * 1024 + gc1, b2 = (size_t)(bn + r2) * 1024 + gc2;
    const int w1 = r1 * 32 + g4 * 8, w2 = r2 * 32 + g4 * 8;

    bf16x8 pAh0, pAh1, pAl0, pAl1, pBh0, pBh1;
    pAh0 = *(const bf16x8*)&Ah[a1]; pAh1 = *(const bf16x8*)&Ah[a2];
    pBh0 = *(const bf16x8*)&Bh[b1]; pBh1 = *(const bf16x8*)&Bh[b2];
    if (comp) { pAl0 = *(const bf16x8*)&Al[a1]; pAl1 = *(const bf16x8*)&Al[a2]; }

    for (int k0 = 0; k0 < 1024; k0 += 32) {
        *(bf16x8*)&sAh[w1] = pAh0; *(bf16x8*)&sAh[w2] = pAh1;
        *(bf16x8*)&sBh[w1] = pBh0; *(bf16x8*)&sBh[w2] = pBh1;
        if (comp) { *(bf16x8*)&sAl[w1] = pAl0; *(bf16x8*)&sAl[w2] = pAl1; }
        __syncthreads();
        if (k0 + 32 < 1024) {
            int kn = k0 + 32;
            pAh0 = *(const bf16x8*)&Ah[a1 + kn]; pAh1 = *(const bf16x8*)&Ah[a2 + kn];
            pBh0 = *(const bf16x8*)&Bh[b1 + kn]; pBh1 = *(const bf16x8*)&Bh[b2 + kn];
            if (comp) { pAl0 = *(const bf16x8*)&Al[a1 + kn]; pAl1 = *(const bf16x8*)&Al[a2 + kn]; }
        }
        bf16x8 fah[4], fal[4], fbh[4];
#pragma unroll
        for (int s = 0; s < 4; s++) {
            int ra = wm * 64 + s * 16 + l16;
            int rb = wn * 64 + s * 16 + l16;
            int ca = (quad ^ (ra & 3)) * 8;
            int cb = (quad ^ (rb & 3)) * 8;
            fah[s] = *(const bf16x8*)&sAh[ra * 32 + ca];
            fbh[s] = *(const bf16x8*)&sBh[rb * 32 + cb];
            if (comp) fal[s] = *(const bf16x8*)&sAl[ra * 32 + ca];
        }
#pragma unroll
        for (int sm = 0; sm < 4; sm++)
#pragma unroll
            for (int sn = 0; sn < 4; sn++) {
                acc[sm][sn] = __builtin_amdgcn_mfma_f32_16x16x32_bf16(fah[sm], fbh[sn], acc[sm][sn], 0, 0, 0);
                if (comp)
                    acc[sm][sn] = __builtin_amdgcn_mfma_f32_16x16x32_bf16(fal[sm], fbh[sn], acc[sm][sn], 0, 0, 0);
            }
        __syncthreads();
    }
#pragma unroll
    for (int sm = 0; sm < 4; sm++) {
        int rowb = bm + wm * 64 + sm * 16 + quad * 4;
        int bb = rowb >> 11, i0 = rowb & 2047;
#pragma unroll
        for (int sn = 0; sn < 4; sn++) {
            int col = bn + wn * 64 + sn * 16 + l16;
            int region = col >> 10;
            int hh = (col >> 6) & 15;
            int d = col & 63;
            if (region == 0) {
#pragma unroll
                for (int r = 0; r < 4; r++) {
                    size_t o = (((size_t)(bb * H_ + hh)) * N_ + i0 + r) * DH_ + d;
                    qh[o] = f2bf(acc[sm][sn][r] * SCALE_);
                }
            } else if (region == 1) {
#pragma unroll
                for (int r = 0; r < 4; r++) {
                    size_t o = (((size_t)(bb * H_ + hh)) * N_ + i0 + r) * DH_ + d;
                    kb[o] = f2bf(acc[sm][sn][r]);
                }
            } else {
                u16x4 pv;
#pragma unroll
                for (int r = 0; r < 4; r++) pv[r] = f2bf(acc[sm][sn][r]);
                *(u16x4*)&vT[(((size_t)(bb * H_ + hh)) * DH_ + d) * N_ + i0] = pv;
            }
        }
    }
}

// ---- stage 3: O(bf16) @ Wo(hi only, 1-term) + bo -> fp32. 128x64 tiles ----
__global__ __launch_bounds__(256) void gemm_out(
    const u16* __restrict__ Ab,
    const u16* __restrict__ Bh,
    const float* __restrict__ bo, float* __restrict__ out)
{
    __shared__ __align__(16) u16 sA[128 * 32], sBh[64 * 32];
    const int tid = threadIdx.x;
    const int wave = tid >> 6, lane = tid & 63;
    const int quad = lane >> 4, l16 = lane & 15;
    const int wm = wave >> 1, wn = wave & 1;
    const int bm = blockIdx.y * 128, bn = blockIdx.x * 64;

    f32x4 acc[4][2];
#pragma unroll
    for (int i = 0; i < 4; i++)
#pragma unroll
        for (int j = 0; j < 2; j++) acc[i][j] = (f32x4){0.f, 0.f, 0.f, 0.f};

    const int row0 = tid >> 2, g4 = tid & 3;
    const int r1 = row0, r2 = row0 + 64;
    const int rb0 = tid >> 2;
    const int gc1 = (g4 ^ (r1 & 3)) * 8, gc2 = (g4 ^ (r2 & 3)) * 8;
    const size_t a1 = (size_t)(bm + r1) * 1024 + gc1, a2 = (size_t)(bm + r2) * 1024 + gc2;
    const size_t bgo = (size_t)(bn + rb0) * 1024 + gc1;
    const int w1 = r1 * 32 + g4 * 8, w2 = r2 * 32 + g4 * 8;
    const int wb = rb0 * 32 + g4 * 8;

    bf16x8 pA0, pA1, pBh0;
    pA0 = *(const bf16x8*)&Ab[a1]; pA1 = *(const bf16x8*)&Ab[a2];
    pBh0 = *(const bf16x8*)&Bh[bgo];

    for (int k0 = 0; k0 < 1024; k0 += 32) {
        *(bf16x8*)&sA[w1] = pA0;  *(bf16x8*)&sA[w2] = pA1;
        *(bf16x8*)&sBh[wb] = pBh0;
        __syncthreads();
        if (k0 + 32 < 1024) {
            int kn = k0 + 32;
            pA0 = *(const bf16x8*)&Ab[a1 + kn]; pA1 = *(const bf16x8*)&Ab[a2 + kn];
            pBh0 = *(const bf16x8*)&Bh[bgo + kn];
        }
        bf16x8 fa[4], fbh[2];
#pragma unroll
        for (int s = 0; s < 4; s++) {
            int ra = wm * 64 + s * 16 + l16;
            int ca = (quad ^ (ra & 3)) * 8;
            fa[s] = *(const bf16x8*)&sA[ra * 32 + ca];
        }
#pragma unroll
        for (int s = 0; s < 2; s++) {
            int rb = wn * 32 + s * 16 + l16;
            int cb = (quad ^ (rb & 3)) * 8;
            fbh[s] = *(const bf16x8*)&sBh[rb * 32 + cb];
        }
#pragma unroll
        for (int sm = 0; sm < 4; sm++)
#pragma unroll
            for (int sn = 0; sn < 2; sn++)
                acc[sm][sn] = __builtin_amdgcn_mfma_f32_16x16x32_bf16(fa[sm], fbh[sn], acc[sm][sn], 0, 0, 0);
        __syncthreads();
    }
#pragma unroll
    for (int sm = 0; sm < 4; sm++) {
        int rowb = bm + wm * 64 + sm * 16 + quad * 4;
#pragma unroll
        for (int sn = 0; sn < 2; sn++) {
            int col = bn + wn * 32 + sn * 16 + l16;
            float bv = bo[col];
#pragma unroll
            for (int r = 0; r < 4; r++)
                out[(size_t)(rowb + r) * 1024 + col] = acc[sm][sn][r] + bv;
        }
    }
}

// ---- stage 2: flash attention. LDS 53248 B -> 3 blocks/CU.
// Bias via swizzled-global coalesced 64B/lane loads (register dbuffered);
// LDV 128 (benign 2x on V frags). Single-term S, LDP 36, pack2.
#define LDK 72    // sK  [128 keys][64 d]  (144B stride: conflict-free frags)
#define LDV 128   // sVt [64 d][128 keys]  (256B stride)
#define LDP 36    // sP  [4 waves][64 q][32 k + 4 pad]

__global__ __launch_bounds__(256, 2) void attn_kernel(
    const u16* __restrict__ qh,
    const u16* __restrict__ kb, const u16* __restrict__ vT,
    const u16* __restrict__ bsw, u16* __restrict__ ob)
{
    __shared__ __align__(16) char smem[53248];
    u16* sK  = (u16*)smem;               // 128*72*2  = 18432
    u16* sVt = (u16*)(smem + 18432);     // 64*128*2  = 16384
    u16* sP  = (u16*)(smem + 34816);     // 4*64*36*2 = 18432
    float* rO = (float*)smem;            // epilogue alias [2][64][68] f32 = 34816
    float* rL = (float*)(smem + 34816);  // [2][64] f32 = 512 (sP dead then)

    const int bh = blockIdx.y, b = bh >> 4, h = bh & 15;   // consecutive x share bh
    const int qt = blockIdx.x, qbase = qt * 64;
    const int tid = threadIdx.x, wave = tid >> 6, lane = tid & 63;
    const int quad = lane >> 4, l16 = lane & 15;

    // Q A-frags (pre-scaled by SCALE), single term
    bf16x8 aq[4][2];
#pragma unroll
    for (int m = 0; m < 4; m++) {
        size_t qo = ((size_t)bh * N_ + qbase + m * 16 + l16) * DH_ + quad * 8;
        aq[m][0] = *(const bf16x8*)&qh[qo];
        aq[m][1] = *(const bf16x8*)&qh[qo + 32];
    }
    f32x4 Oacc[4][4], lacc[4];
#pragma unroll
    for (int m = 0; m < 4; m++) {
        lacc[m] = (f32x4){0.f, 0.f, 0.f, 0.f};
#pragma unroll
        for (int nd = 0; nd < 4; nd++) Oacc[m][nd] = (f32x4){0.f, 0.f, 0.f, 0.f};
    }
    bf16x8 ones;
#pragma unroll
    for (int i = 0; i < 8; i++) ones[i] = (short)0x3F80;

    const int rK = tid >> 3, cK = (tid & 7) * 8;    // K staging rows +it*32
    const int rV = tid >> 4, cV = (tid & 15) * 8;   // V staging rows +it*16
    const size_t kgbase = (size_t)bh * N_ * DH_;
    const size_t vgbase = (size_t)bh * DH_ * N_;
    // swizzled bias: layout ((((b*32+qt)*16 + jt)*4 + wv)*64 + lane)*32;
    // per-(b,qt) stride = 16*4*2048 = 131072 u16; jt stride = 4*2048 = 8192.
    const size_t bswb = (size_t)(b * 32 + qt) * 131072 + (size_t)wave * 2048
                        + (size_t)lane * 32;

    // prologue: register prefetch of jtile 0
    bf16x8 pK[4], pV[4];
    u16x8 cB[4], nB[4];
#pragma unroll
    for (int it = 0; it < 4; it++) {
        pK[it] = *(const bf16x8*)&kb[kgbase + (size_t)(rK + it * 32) * DH_ + cK];
        pV[it] = *(const bf16x8*)&vT[vgbase + (size_t)(rV + it * 16) * N_ + cV];
    }
#pragma unroll
    for (int c = 0; c < 4; c++) cB[c] = *(const u16x8*)&bsw[bswb + c * 8];

    for (int jt = 0; jt < 16; jt++) {
        // commit staged K/V
#pragma unroll
        for (int it = 0; it < 4; it++) {
            *(bf16x8*)&sK[(rK + it * 32) * LDK + cK] = pK[it];
            *(bf16x8*)&sVt[(rV + it * 16) * LDV + cV] = pV[it];
        }
        __syncthreads();
        // prefetch next jtile (coalesced; latency hidden by compute)
        {
            int jn = (jt + 1) & 15;
            int j0n = jn * 128;
#pragma unroll
            for (int it = 0; it < 4; it++) {
                pK[it] = *(const bf16x8*)&kb[kgbase + (size_t)(j0n + rK + it * 32) * DH_ + cK];
                pV[it] = *(const bf16x8*)&vT[vgbase + (size_t)(rV + it * 16) * N_ + j0n + cV];
            }
            size_t bb = bswb + (size_t)jn * 8192;   // jn*4*2048
#pragma unroll
            for (int c = 0; c < 4; c++) nB[c] = *(const u16x8*)&bsw[bb + c * 8];
        }
        // per-jtile frags (loaded once, reused across all m)
        bf16x8 kf[2][2], vf[4];
#pragma unroll
        for (int n = 0; n < 2; n++)
#pragma unroll
            for (int s = 0; s < 2; s++)
                kf[n][s] = *(const bf16x8*)&sK[(wave * 32 + n * 16 + l16) * LDK + s * 32 + quad * 8];
#pragma unroll
        for (int nd = 0; nd < 4; nd++)
            vf[nd] = *(const bf16x8*)&sVt[(nd * 16 + l16) * LDV + wave * 32 + quad * 8];

        u16* pw = sP + wave * 64 * LDP;
#pragma unroll
        for (int m = 0; m < 4; m++) {
            f32x4 S0 = (f32x4){0.f, 0.f, 0.f, 0.f};
            f32x4 S1 = (f32x4){0.f, 0.f, 0.f, 0.f};
#pragma unroll
            for (int s = 0; s < 2; s++) {
                S0 = __builtin_amdgcn_mfma_f32_16x16x32_bf16(aq[m][s], kf[0][s], S0, 0, 0, 0);
                S1 = __builtin_amdgcn_mfma_f32_16x16x32_bf16(aq[m][s], kf[1][s], S1, 0, 0, 0);
            }
            // bias from registers: cB[m>>1] = n0, cB[2+(m>>1)] = n1; elem (m&1)*4+r
#pragma unroll
            for (int r = 0; r < 4; r++) {
                S0[r] = __expf(S0[r] + bf2f(cB[m >> 1][(m & 1) * 4 + r]));
                S1[r] = __expf(S1[r] + bf2f(cB[2 + (m >> 1)][(m & 1) * 4 + r]));
            }
#pragma unroll
            for (int r = 0; r < 4; r++) {
                u16 lo, hi;
                pack2(S0[r], S1[r], lo, hi);
                pw[(m * 16 + quad * 4 + r) * LDP + l16]      = lo;
                pw[(m * 16 + quad * 4 + r) * LDP + 16 + l16] = hi;
            }
            bf16x8 pa = *(const bf16x8*)&pw[(m * 16 + l16) * LDP + quad * 8];
            lacc[m] = __builtin_amdgcn_mfma_f32_16x16x32_bf16(pa, ones, lacc[m], 0, 0, 0);
#pragma unroll
            for (int nd = 0; nd < 4; nd++)
                Oacc[m][nd] = __builtin_amdgcn_mfma_f32_16x16x32_bf16(pa, vf[nd], Oacc[m][nd], 0, 0, 0);
        }
#pragma unroll
        for (int c = 0; c < 4; c++) cB[c] = nB[c];
        __syncthreads();
    }

    // ---- epilogue: 2-stage tree reduction (fits 53248-byte smem) ----
    if (wave >= 2) {
        int slot = wave - 2;
#pragma unroll
        for (int m = 0; m < 4; m++) {
#pragma unroll
            for (int nd = 0; nd < 4; nd++)
#pragma unroll
                for (int r = 0; r < 4; r++)
                    rO[(slot * 64 + m * 16 + quad * 4 + r) * 68 + nd * 16 + l16] = Oacc[m][nd][r];
            if (l16 == 0)
#pragma unroll
                for (int r = 0; r < 4; r++)
                    rL[slot * 64 + m * 16 + quad * 4 + r] = lacc[m][r];
        }
    }
    __syncthreads();
    if (wave < 2) {
        int slot = wave;
#pragma unroll
        for (int m = 0; m < 4; m++) {
#pragma unroll
            for (int nd = 0; nd < 4; nd++)
#pragma unroll
                for (int r = 0; r < 4; r++) {
                    int idx = (slot * 64 + m * 16 + quad * 4 + r) * 68 + nd * 16 + l16;
                    rO[idx] += Oacc[m][nd][r];
                }
            if (l16 == 0)
#pragma unroll
                for (int r = 0; r < 4; r++)
                    rL[slot * 64 + m * 16 + quad * 4 + r] += lacc[m][r];
        }
    }
    __syncthreads();
    {
        const int q = tid >> 2, dg = (tid & 3) * 16;
        float l = rL[q] + rL[64 + q];
        float inv = 1.f / l;
        f32x4 s[4];
#pragma unroll
        for (int i4 = 0; i4 < 4; i4++) {
            s[i4] = *(const f32x4*)&rO[(size_t)q * 68 + dg + i4 * 4];
            f32x4 v = *(const f32x4*)&rO[(size_t)(64 + q) * 68 + dg + i4 * 4];
            s[i4] += v;
        }
        size_t obase = ((size_t)b * N_ + qbase + q) * INNER_ + h * 64 + dg;
#pragma unroll
        for (int i4 = 0; i4 < 4; i4++) {
            u16x4 o4;
#pragma unroll
            for (int r = 0; r < 4; r++) o4[r] = f2bf(s[i4][r] * inv);
            *(u16x4*)&ob[obase + i4 * 4] = o4;
        }
    }
}

extern "C" void kernel_launch(void* const* d_in, const int* in_sizes, int n_in,
                              void* d_out, int out_size, void* d_ws, size_t ws_size,
                              hipStream_t stream)
{
    const float* x    = (const float*)d_in[0];
    const float* bias = (const float*)d_in[1];
    const int*   mask = (const int*)d_in[2];
    const float* Wq   = (const float*)d_in[3];
    const float* Wkv  = (const float*)d_in[4];
    const float* Wo   = (const float*)d_in[5];
    const float* bo   = (const float*)d_in[6];
    float* out = (float*)d_out;

    char* w = (char*)d_ws;
    const size_t MB = 1024 * 1024;
    u16* q_h   = (u16*)(w);             //  0..8   [32][2048][64]
    u16* k_b   = (u16*)(w + 16 * MB);
    u16* v_T   = (u16*)(w + 24 * MB);   // [32][64][2048]
    u16* xs_h  = (u16*)(w + 32 * MB);
    u16* xs_l  = (u16*)(w + 40 * MB);
    u16* wT_h  = (u16*)(w + 48 * MB);   // [3072][1024]
    u16* wT_l  = (u16*)(w + 54 * MB);
    u16* woT_h = (u16*)(w + 60 * MB);
    u16* woT_l = (u16*)(w + 62 * MB);
    u16* o_b   = (u16*)(w + 64 * MB);   // [2][2048][1024]

    const size_t bsw_bytes = (size_t)2 * N_ * N_ * sizeof(u16);   // 16.78 MB
    const bool concurrent = ws_size >= 72 * MB + bsw_bytes;

    prep_kernel<<<8192, 256, 0, stream>>>(x, xs_h, xs_l, Wq, Wkv, Wo, wT_h, wT_l, woT_h, woT_l);

    if (concurrent) {
        u16* bsw = (u16*)(w + 72 * MB);
        gemm_qkv_bias<<<2816, 256, 0, stream>>>(1, xs_h, xs_l, wT_h,
                                                q_h, k_b, v_T, bias, mask, bsw);
        attn_kernel<<<dim3(32, 32), 256, 0, stream>>>(q_h, k_b, v_T, bsw, o_b);
    } else {
        u16* bsw = (u16*)(w + 32 * MB);   // aliases xs (dead after gemm) — sequential only
        gemm_qkv_bias<<<768, 256, 0, stream>>>(0, xs_h, xs_l, wT_h,
                                               q_h, k_b, v_T, bias, mask, bsw);
        gemm_qkv_bias<<<2048, 256, 0, stream>>>(2, xs_h, xs_l, wT_h,
                                                q_h, k_b, v_T, bias, mask, bsw);
        attn_kernel<<<dim3(32, 32), 256, 0, stream>>>(q_h, k_b, v_T, bsw, o_b);
    }
    gemm_out<<<dim3(16, 32), 256, 0, stream>>>(o_b, woT_h, bo, out);
}

// Round 13
// 280.181 us; speedup vs baseline: 1.0178x; 1.0178x over previous
//
#include <hip/hip_runtime.h>
#include <hip/hip_bf16.h>
#include <stdint.h>

#define B_     2
#define N_     2048
#define QD_    1024
#define H_     16
#define DH_    64
#define INNER_ 1024
#define SCALE_ 0.125f

typedef unsigned short u16;
typedef __attribute__((ext_vector_type(8))) short bf16x8;   // 8 bf16 = 4 VGPRs
typedef __attribute__((ext_vector_type(4))) float f32x4;    // MFMA C/D frag
typedef __attribute__((ext_vector_type(4))) unsigned short u16x4;
typedef __attribute__((ext_vector_type(8))) unsigned short u16x8;

// ---- bf16 helpers (RNE) ----
__device__ inline u16 f2bf(float f) {
    union { float f; uint32_t u; } c; c.f = f;
    uint32_t r = c.u + 0x7FFFu + ((c.u >> 16) & 1u);
    return (u16)(r >> 16);
}
__device__ inline float bf2f(u16 s) {
    union { uint32_t u; float f; } c; c.u = ((uint32_t)s) << 16;
    return c.f;
}
__device__ inline void split2(float v, u16 &h, u16 &l) {
    u16 hs = f2bf(v);
    h = hs;
    l = f2bf(v - bf2f(hs));
}
// packed RNE f32x2 -> bf16x2 (v_cvt_pk_bf16_f32 on gfx950)
__device__ inline void pack2(float a, float b, u16 &lo, u16 &hi) {
    float2 f; f.x = a; f.y = b;
    union { __hip_bfloat162 v; u16 u[2]; } c;
    c.v = __float22bfloat162_rn(f);
    lo = c.u[0]; hi = c.u[1];
}

// ---- prep: split_x (blocks 0..4095) + W transposes (blocks 4096..8191) ----
__global__ __launch_bounds__(256) void prep_kernel(
    const float* __restrict__ x, u16* __restrict__ xh, u16* __restrict__ xl,
    const float* __restrict__ Wq, const float* __restrict__ Wkv, const float* __restrict__ Wo,
    u16* __restrict__ wTh, u16* __restrict__ wTl,
    u16* __restrict__ woTh, u16* __restrict__ woTl)
{
    __shared__ float t[32][33];
    const int blk = blockIdx.x, tid = threadIdx.x;
    if (blk < 4096) {
        int idx = blk * 256 + tid;
        float4 v = ((const float4*)x)[idx];
        u16x4 hv, lv; u16 h, l;
        split2(v.x, h, l); hv.x = h; lv.x = l;
        split2(v.y, h, l); hv.y = h; lv.y = l;
        split2(v.z, h, l); hv.z = h; lv.z = l;
        split2(v.w, h, l); hv.w = h; lv.w = l;
        ((u16x4*)xh)[idx] = hv;
        ((u16x4*)xl)[idx] = lv;
        return;
    }
    int local = blk - 4096;
    const float* src; u16 *dhi, *dlo; int C, bx, by;
    if (local < 1024)      { src = Wq;  dhi = wTh;                dlo = wTl;                C = 1024; by = local >> 5; bx = local & 31; }
    else if (local < 3072) { int l2 = local - 1024; src = Wkv; dhi = wTh + 1024 * 1024; dlo = wTl + 1024 * 1024; C = 2048; by = l2 >> 6; bx = l2 & 63; }
    else                   { int l2 = local - 3072; src = Wo;  dhi = woTh;               dlo = woTl;               C = 1024; by = l2 >> 5; bx = l2 & 31; }
    const int x0 = bx * 32, y0 = by * 32;
    const int tx = tid & 31, ty = tid >> 5;
    for (int yy = ty; yy < 32; yy += 8)
        t[yy][tx] = src[(size_t)(y0 + yy) * C + x0 + tx];
    __syncthreads();
    for (int i = ty; i < 32; i += 8) {
        float v = t[tx][i];
        u16 h, l; split2(v, h, l);
        size_t o = (size_t)(x0 + i) * 1024 + y0 + tx;
        dhi[o] = h; dlo[o] = l;
    }
}

// ---- stage 1: GEMM x @ [Wq|Wkv] + co-scheduled bias swizzle.
// Q cols (bx<8): 2-term; KV cols: 1-term.
// Bias layout (u16): bsw[((((b*32+qt)*16 + jt)*4 + wv)*64 + lane)*32 + n*16 + m*4 + qr]
__global__ __launch_bounds__(256) void gemm_qkv_bias(
    int mode,
    const u16* __restrict__ Ah, const u16* __restrict__ Al,
    const u16* __restrict__ Bh,
    u16* __restrict__ qh,
    u16* __restrict__ kb, u16* __restrict__ vT,
    const float* __restrict__ bias, const int* __restrict__ mask,
    u16* __restrict__ bsw)
{
    __shared__ __align__(16) char smem[24576];
    const int tid = threadIdx.x;

    int gid = -1, bid = -1;
    if (mode == 1) {
        if (blockIdx.x < 768) gid = blockIdx.x; else bid = blockIdx.x - 768;
    } else if (mode == 0) gid = blockIdx.x;
    else bid = blockIdx.x;

    if (bid >= 0) {
        float (*t)[65] = (float(*)[65])smem;   // 64x65 fp32 = 16640 <= 24576
        const int b = bid >> 10, rest = bid & 1023;
        const int k0 = (rest & 31) * 64, q0 = (rest >> 5) * 64;
#pragma unroll
        for (int it = 0; it < 16; it++) {
            int idx = it * 256 + tid;
            int qq = idx >> 6, kk = idx & 63;
            t[qq][kk] = bias[((size_t)b * N_ + q0 + qq) * N_ + k0 + kk];
        }
        __syncthreads();
        const u16 NEG = f2bf(-1e30f);
        const int qt = q0 >> 6, jt = k0 >> 7, w0 = (k0 >> 5) & 3;
        const int p = tid >> 1, hf = tid & 1;          // p: (wv,lane) pair; hf = n
        const int wv = w0 + (p >> 6), lane = p & 63;
        const int quad = lane >> 4, l16 = lane & 15;
        const int kk = (p >> 6) * 32 + hf * 16 + l16;  // key - k0, in 0..63
        const int mok = mask[b * N_ + k0 + kk];
        u16x8 o0, o1;
#pragma unroll
        for (int i = 0; i < 8; i++) {
            int m = i >> 2, qr = i & 3;
            int qq = m * 16 + quad * 4 + qr;
            o0[i] = mok ? f2bf(t[qq][kk]) : NEG;
        }
#pragma unroll
        for (int i = 0; i < 8; i++) {
            int m = 2 + (i >> 2), qr = i & 3;
            int qq = m * 16 + quad * 4 + qr;
            o1[i] = mok ? f2bf(t[qq][kk]) : NEG;
        }
        size_t ob = ((((size_t)b * 32 + qt) * 16 + jt) * 4 + wv) * 2048
                    + (size_t)lane * 32 + hf * 16;
        *(u16x8*)&bsw[ob]     = o0;
        *(u16x8*)&bsw[ob + 8] = o1;
        return;
    }

    u16* sAh = (u16*)smem;
    u16* sAl = (u16*)(smem + 8192);
    u16* sBh = (u16*)(smem + 16384);
    const int wave = tid >> 6, lane = tid & 63;
    const int quad = lane >> 4, l16 = lane & 15;
    const int wm = wave >> 1, wn = wave & 1;
    const int bx = gid % 24, by = gid / 24;
    const int bm = by * 128, bn = bx * 128;
    const bool comp = (bx < 8);

    f32x4 acc[4][4];
#pragma unroll
    for (int i = 0; i < 4; i++)
#pragma unroll
        for (int j = 0; j < 4; j++) acc[i][j] = (f32x4){0.f, 0.f, 0.f, 0.f};

    const int row0 = tid >> 2, g4 = tid & 3;
    const int r1 = row0, r2 = row0 + 64;
    const int gc1 = (g4 ^ (r1 & 3)) * 8, gc2 = (g4 ^ (r2 & 3)) * 8;
    const size_t a1 = (size_t)(bm + r1) * 1024 + gc1, a2 = (size_t)(bm + r2) * 1024 + gc2;
    const size_t b1 = (size_t)(bn + r1) * 1024 + gc1, b2 = (size_t)(bn + r2) * 1024 + gc2;
    const int w1 = r1 * 32 + g4 * 8, w2 = r2 * 32 + g4 * 8;

    bf16x8 pAh0, pAh1, pAl0, pAl1, pBh0, pBh1;
    pAh0 = *(const bf16x8*)&Ah[a1]; pAh1 = *(const bf16x8*)&Ah[a2];
    pBh0 = *(const bf16x8*)&Bh[b1]; pBh1 = *(const bf16x8*)&Bh[b2];
    if (comp) { pAl0 = *(const bf16x8*)&Al[a1]; pAl1 = *(const bf16x8*)&Al[a2]; }

    for (int k0 = 0; k0 < 1024; k0 += 32) {
        *(bf16x8*)&sAh[w1] = pAh0; *(bf16x8*)&sAh[w2] = pAh1;
        *(bf16x8*)&sBh[w1] = pBh0; *(bf16x8*)&sBh[w2] = pBh1;
        if (comp) { *(bf16x8*)&sAl[w1] = pAl0; *(bf16x8*)&sAl[w2] = pAl1; }
        __syncthreads();
        if (k0 + 32 < 1024) {
            int kn = k0 + 32;
            pAh0 = *(const bf16x8*)&Ah[a1 + kn]; pAh1 = *(const bf16x8*)&Ah[a2 + kn];
            pBh0 = *(const bf16x8*)&Bh[b1 + kn]; pBh1 = *(const bf16x8*)&Bh[b2 + kn];
            if (comp) { pAl0 = *(const bf16x8*)&Al[a1 + kn]; pAl1 = *(const bf16x8*)&Al[a2 + kn]; }
        }
        bf16x8 fah[4], fal[4], fbh[4];
#pragma unroll
        for (int s = 0; s < 4; s++) {
            int ra = wm * 64 + s * 16 + l16;
            int rb = wn * 64 + s * 16 + l16;
            int ca = (quad ^ (ra & 3)) * 8;
            int cb = (quad ^ (rb & 3)) * 8;
            fah[s] = *(const bf16x8*)&sAh[ra * 32 + ca];
            fbh[s] = *(const bf16x8*)&sBh[rb * 32 + cb];
            if (comp) fal[s] = *(const bf16x8*)&sAl[ra * 32 + ca];
        }
#pragma unroll
        for (int sm = 0; sm < 4; sm++)
#pragma unroll
            for (int sn = 0; sn < 4; sn++) {
                acc[sm][sn] = __builtin_amdgcn_mfma_f32_16x16x32_bf16(fah[sm], fbh[sn], acc[sm][sn], 0, 0, 0);
                if (comp)
                    acc[sm][sn] = __builtin_amdgcn_mfma_f32_16x16x32_bf16(fal[sm], fbh[sn], acc[sm][sn], 0, 0, 0);
            }
        __syncthreads();
    }
#pragma unroll
    for (int sm = 0; sm < 4; sm++) {
        int rowb = bm + wm * 64 + sm * 16 + quad * 4;
        int bb = rowb >> 11, i0 = rowb & 2047;
#pragma unroll
        for (int sn = 0; sn < 4; sn++) {
            int col = bn + wn * 64 + sn * 16 + l16;
            int region = col >> 10;
            int hh = (col >> 6) & 15;
            int d = col & 63;
            if (region == 0) {
#pragma unroll
                for (int r = 0; r < 4; r++) {
                    size_t o = (((size_t)(bb * H_ + hh)) * N_ + i0 + r) * DH_ + d;
                    qh[o] = f2bf(acc[sm][sn][r] * SCALE_);
                }
            } else if (region == 1) {
#pragma unroll
                for (int r = 0; r < 4; r++) {
                    size_t o = (((size_t)(bb * H_ + hh)) * N_ + i0 + r) * DH_ + d;
                    kb[o] = f2bf(acc[sm][sn][r]);
                }
            } else {
                u16x4 pv;
#pragma unroll
                for (int r = 0; r < 4; r++) pv[r] = f2bf(acc[sm][sn][r]);
                *(u16x4*)&vT[(((size_t)(bb * H_ + hh)) * DH_ + d) * N_ + i0] = pv;
            }
        }
    }
}

// ---- stage 3: O(bf16) @ Wo(hi only, 1-term) + bo -> fp32. 128x64 tiles ----
__global__ __launch_bounds__(256) void gemm_out(
    const u16* __restrict__ Ab,
    const u16* __restrict__ Bh,
    const float* __restrict__ bo, float* __restrict__ out)
{
    __shared__ __align__(16) u16 sA[128 * 32], sBh[64 * 32];
    const int tid = threadIdx.x;
    const int wave = tid >> 6, lane = tid & 63;
    const int quad = lane >> 4, l16 = lane & 15;
    const int wm = wave >> 1, wn = wave & 1;
    const int bm = blockIdx.y * 128, bn = blockIdx.x * 64;

    f32x4 acc[4][2];
#pragma unroll
    for (int i = 0; i < 4; i++)
#pragma unroll
        for (int j = 0; j < 2; j++) acc[i][j] = (f32x4){0.f, 0.f, 0.f, 0.f};

    const int row0 = tid >> 2, g4 = tid & 3;
    const int r1 = row0, r2 = row0 + 64;
    const int rb0 = tid >> 2;
    const int gc1 = (g4 ^ (r1 & 3)) * 8, gc2 = (g4 ^ (r2 & 3)) * 8;
    const size_t a1 = (size_t)(bm + r1) * 1024 + gc1, a2 = (size_t)(bm + r2) * 1024 + gc2;
    const size_t bgo = (size_t)(bn + rb0) * 1024 + gc1;
    const int w1 = r1 * 32 + g4 * 8, w2 = r2 * 32 + g4 * 8;
    const int wb = rb0 * 32 + g4 * 8;

    bf16x8 pA0, pA1, pBh0;
    pA0 = *(const bf16x8*)&Ab[a1]; pA1 = *(const bf16x8*)&Ab[a2];
    pBh0 = *(const bf16x8*)&Bh[bgo];

    for (int k0 = 0; k0 < 1024; k0 += 32) {
        *(bf16x8*)&sA[w1] = pA0;  *(bf16x8*)&sA[w2] = pA1;
        *(bf16x8*)&sBh[wb] = pBh0;
        __syncthreads();
        if (k0 + 32 < 1024) {
            int kn = k0 + 32;
            pA0 = *(const bf16x8*)&Ab[a1 + kn]; pA1 = *(const bf16x8*)&Ab[a2 + kn];
            pBh0 = *(const bf16x8*)&Bh[bgo + kn];
        }
        bf16x8 fa[4], fbh[2];
#pragma unroll
        for (int s = 0; s < 4; s++) {
            int ra = wm * 64 + s * 16 + l16;
            int ca = (quad ^ (ra & 3)) * 8;
            fa[s] = *(const bf16x8*)&sA[ra * 32 + ca];
        }
#pragma unroll
        for (int s = 0; s < 2; s++) {
            int rb = wn * 32 + s * 16 + l16;
            int cb = (quad ^ (rb & 3)) * 8;
            fbh[s] = *(const bf16x8*)&sBh[rb * 32 + cb];
        }
#pragma unroll
        for (int sm = 0; sm < 4; sm++)
#pragma unroll
            for (int sn = 0; sn < 2; sn++)
                acc[sm][sn] = __builtin_amdgcn_mfma_f32_16x16x32_bf16(fa[sm], fbh[sn], acc[sm][sn], 0, 0, 0);
        __syncthreads();
    }
#pragma unroll
    for (int sm = 0; sm < 4; sm++) {
        int rowb = bm + wm * 64 + sm * 16 + quad * 4;
#pragma unroll
        for (int sn = 0; sn < 2; sn++) {
            int col = bn + wn * 32 + sn * 16 + l16;
            float bv = bo[col];
#pragma unroll
            for (int r = 0; r < 4; r++)
                out[(size_t)(rowb + r) * 1024 + col] = acc[sm][sn][r] + bv;
        }
    }
}

// ---- stage 2: flash attention. LDS 53248 B -> 3 blocks/CU.
// sVt XOR-swizzled (group g of row r stored at g^(r&7)): restores 8-bank
// spread for V frag reads at stride 128 (fixes R12's 16-way conflict).
#define LDK 72    // sK  [128 keys][64 d]  (144B stride: conflict-free frags)
#define LDV 128   // sVt [64 d][128 keys]  (256B stride, XOR-swizzled groups)
#define LDP 36    // sP  [4 waves][64 q][32 k + 4 pad]

__global__ __launch_bounds__(256, 2) void attn_kernel(
    const u16* __restrict__ qh,
    const u16* __restrict__ kb, const u16* __restrict__ vT,
    const u16* __restrict__ bsw, u16* __restrict__ ob)
{
    __shared__ __align__(16) char smem[53248];
    u16* sK  = (u16*)smem;               // 128*72*2  = 18432
    u16* sVt = (u16*)(smem + 18432);     // 64*128*2  = 16384
    u16* sP  = (u16*)(smem + 34816);     // 4*64*36*2 = 18432
    float* rO = (float*)smem;            // epilogue alias [2][64][68] f32 = 34816
    float* rL = (float*)(smem + 34816);  // [2][64] f32 = 512 (sP dead then)

    const int bh = blockIdx.y, b = bh >> 4, h = bh & 15;   // consecutive x share bh
    const int qt = blockIdx.x, qbase = qt * 64;
    const int tid = threadIdx.x, wave = tid >> 6, lane = tid & 63;
    const int quad = lane >> 4, l16 = lane & 15;

    // Q A-frags (pre-scaled by SCALE), single term
    bf16x8 aq[4][2];
#pragma unroll
    for (int m = 0; m < 4; m++) {
        size_t qo = ((size_t)bh * N_ + qbase + m * 16 + l16) * DH_ + quad * 8;
        aq[m][0] = *(const bf16x8*)&qh[qo];
        aq[m][1] = *(const bf16x8*)&qh[qo + 32];
    }
    f32x4 Oacc[4][4], lacc[4];
#pragma unroll
    for (int m = 0; m < 4; m++) {
        lacc[m] = (f32x4){0.f, 0.f, 0.f, 0.f};
#pragma unroll
        for (int nd = 0; nd < 4; nd++) Oacc[m][nd] = (f32x4){0.f, 0.f, 0.f, 0.f};
    }
    bf16x8 ones;
#pragma unroll
    for (int i = 0; i < 8; i++) ones[i] = (short)0x3F80;

    const int rK = tid >> 3, cK = (tid & 7) * 8;    // K staging rows +it*32
    const int rV = tid >> 4;                        // V staging rows +it*16
    const int vg = tid & 15;                        // V logical group (8 elems)
    const int cV = vg * 8;                          // global col offset
    const int vsw = (vg ^ (rV & 7)) * 8;            // swizzled LDS col ((it*16)&7==0)
    const int vrg = ((wave * 4 + quad) ^ (l16 & 7)) * 8;  // swizzled read col
    const size_t kgbase = (size_t)bh * N_ * DH_;
    const size_t vgbase = (size_t)bh * DH_ * N_;
    // swizzled bias: per-(b,qt) stride 16*4*2048 = 131072 u16; jt stride 8192.
    const size_t bswb = (size_t)(b * 32 + qt) * 131072 + (size_t)wave * 2048
                        + (size_t)lane * 32;

    // prologue: register prefetch of jtile 0
    bf16x8 pK[4], pV[4];
    u16x8 cB[4], nB[4];
#pragma unroll
    for (int it = 0; it < 4; it++) {
        pK[it] = *(const bf16x8*)&kb[kgbase + (size_t)(rK + it * 32) * DH_ + cK];
        pV[it] = *(const bf16x8*)&vT[vgbase + (size_t)(rV + it * 16) * N_ + cV];
    }
#pragma unroll
    for (int c = 0; c < 4; c++) cB[c] = *(const u16x8*)&bsw[bswb + c * 8];

    for (int jt = 0; jt < 16; jt++) {
        // commit staged K/V (V goes to swizzled slots)
#pragma unroll
        for (int it = 0; it < 4; it++) {
            *(bf16x8*)&sK[(rK + it * 32) * LDK + cK] = pK[it];
            *(bf16x8*)&sVt[(rV + it * 16) * LDV + vsw] = pV[it];
        }
        __syncthreads();
        // prefetch next jtile (coalesced; latency hidden by compute)
        {
            int jn = (jt + 1) & 15;
            int j0n = jn * 128;
#pragma unroll
            for (int it = 0; it < 4; it++) {
                pK[it] = *(const bf16x8*)&kb[kgbase + (size_t)(j0n + rK + it * 32) * DH_ + cK];
                pV[it] = *(const bf16x8*)&vT[vgbase + (size_t)(rV + it * 16) * N_ + j0n + cV];
            }
            size_t bb = bswb + (size_t)jn * 8192;   // jn*4*2048
#pragma unroll
            for (int c = 0; c < 4; c++) nB[c] = *(const u16x8*)&bsw[bb + c * 8];
        }
        // per-jtile frags (loaded once, reused across all m)
        bf16x8 kf[2][2], vf[4];
#pragma unroll
        for (int n = 0; n < 2; n++)
#pragma unroll
            for (int s = 0; s < 2; s++)
                kf[n][s] = *(const bf16x8*)&sK[(wave * 32 + n * 16 + l16) * LDK + s * 32 + quad * 8];
#pragma unroll
        for (int nd = 0; nd < 4; nd++)
            vf[nd] = *(const bf16x8*)&sVt[(nd * 16 + l16) * LDV + vrg];

        u16* pw = sP + wave * 64 * LDP;
#pragma unroll
        for (int m = 0; m < 4; m++) {
            f32x4 S0 = (f32x4){0.f, 0.f, 0.f, 0.f};
            f32x4 S1 = (f32x4){0.f, 0.f, 0.f, 0.f};
#pragma unroll
            for (int s = 0; s < 2; s++) {
                S0 = __builtin_amdgcn_mfma_f32_16x16x32_bf16(aq[m][s], kf[0][s], S0, 0, 0, 0);
                S1 = __builtin_amdgcn_mfma_f32_16x16x32_bf16(aq[m][s], kf[1][s], S1, 0, 0, 0);
            }
            // bias from registers: cB[m>>1] = n0, cB[2+(m>>1)] = n1; elem (m&1)*4+r
#pragma unroll
            for (int r = 0; r < 4; r++) {
                S0[r] = __expf(S0[r] + bf2f(cB[m >> 1][(m & 1) * 4 + r]));
                S1[r] = __expf(S1[r] + bf2f(cB[2 + (m >> 1)][(m & 1) * 4 + r]));
            }
#pragma unroll
            for (int r = 0; r < 4; r++) {
                u16 lo, hi;
                pack2(S0[r], S1[r], lo, hi);
                pw[(m * 16 + quad * 4 + r) * LDP + l16]      = lo;
                pw[(m * 16 + quad * 4 + r) * LDP + 16 + l16] = hi;
            }
            bf16x8 pa = *(const bf16x8*)&pw[(m * 16 + l16) * LDP + quad * 8];
            lacc[m] = __builtin_amdgcn_mfma_f32_16x16x32_bf16(pa, ones, lacc[m], 0, 0, 0);
#pragma unroll
            for (int nd = 0; nd < 4; nd++)
                Oacc[m][nd] = __builtin_amdgcn_mfma_f32_16x16x32_bf16(pa, vf[nd], Oacc[m][nd], 0, 0, 0);
        }
#pragma unroll
        for (int c = 0; c < 4; c++) cB[c] = nB[c];
        __syncthreads();
    }

    // ---- epilogue: 2-stage tree reduction (fits 53248-byte smem) ----
    if (wave >= 2) {
        int slot = wave - 2;
#pragma unroll
        for (int m = 0; m < 4; m++) {
#pragma unroll
            for (int nd = 0; nd < 4; nd++)
#pragma unroll
                for (int r = 0; r < 4; r++)
                    rO[(slot * 64 + m * 16 + quad * 4 + r) * 68 + nd * 16 + l16] = Oacc[m][nd][r];
            if (l16 == 0)
#pragma unroll
                for (int r = 0; r < 4; r++)
                    rL[slot * 64 + m * 16 + quad * 4 + r] = lacc[m][r];
        }
    }
    __syncthreads();
    if (wave < 2) {
        int slot = wave;
#pragma unroll
        for (int m = 0; m < 4; m++) {
#pragma unroll
            for (int nd = 0; nd < 4; nd++)
#pragma unroll
                for (int r = 0; r < 4; r++) {
                    int idx = (slot * 64 + m * 16 + quad * 4 + r) * 68 + nd * 16 + l16;
                    rO[idx] += Oacc[m][nd][r];
                }
            if (l16 == 0)
#pragma unroll
                for (int r = 0; r < 4; r++)
                    rL[slot * 64 + m * 16 + quad * 4 + r] += lacc[m][r];
        }
    }
    __syncthreads();
    {
        const int q = tid >> 2, dg = (tid & 3) * 16;
        float l = rL[q] + rL[64 + q];
        float inv = 1.f / l;
        f32x4 s[4];
#pragma unroll
        for (int i4 = 0; i4 < 4; i4++) {
            s[i4] = *(const f32x4*)&rO[(size_t)q * 68 + dg + i4 * 4];
            f32x4 v = *(const f32x4*)&rO[(size_t)(64 + q) * 68 + dg + i4 * 4];
            s[i4] += v;
        }
        size_t obase = ((size_t)b * N_ + qbase + q) * INNER_ + h * 64 + dg;
#pragma unroll
        for (int i4 = 0; i4 < 4; i4++) {
            u16x4 o4;
#pragma unroll
            for (int r = 0; r < 4; r++) o4[r] = f2bf(s[i4][r] * inv);
            *(u16x4*)&ob[obase + i4 * 4] = o4;
        }
    }
}

extern "C" void kernel_launch(void* const* d_in, const int* in_sizes, int n_in,
                              void* d_out, int out_size, void* d_ws, size_t ws_size,
                              hipStream_t stream)
{
    const float* x    = (const float*)d_in[0];
    const float* bias = (const float*)d_in[1];
    const int*   mask = (const int*)d_in[2];
    const float* Wq   = (const float*)d_in[3];
    const float* Wkv  = (const float*)d_in[4];
    const float* Wo   = (const float*)d_in[5];
    const float* bo   = (const float*)d_in[6];
    float* out = (float*)d_out;

    char* w = (char*)d_ws;
    const size_t MB = 1024 * 1024;
    u16* q_h   = (u16*)(w);             //  0..8   [32][2048][64]
    u16* k_b   = (u16*)(w + 16 * MB);
    u16* v_T   = (u16*)(w + 24 * MB);   // [32][64][2048]
    u16* xs_h  = (u16*)(w + 32 * MB);
    u16* xs_l  = (u16*)(w + 40 * MB);
    u16* wT_h  = (u16*)(w + 48 * MB);   // [3072][1024]
    u16* wT_l  = (u16*)(w + 54 * MB);
    u16* woT_h = (u16*)(w + 60 * MB);
    u16* woT_l = (u16*)(w + 62 * MB);
    u16* o_b   = (u16*)(w + 64 * MB);   // [2][2048][1024]

    const size_t bsw_bytes = (size_t)2 * N_ * N_ * sizeof(u16);   // 16.78 MB
    const bool concurrent = ws_size >= 72 * MB + bsw_bytes;

    prep_kernel<<<8192, 256, 0, stream>>>(x, xs_h, xs_l, Wq, Wkv, Wo, wT_h, wT_l, woT_h, woT_l);

    if (concurrent) {
        u16* bsw = (u16*)(w + 72 * MB);
        gemm_qkv_bias<<<2816, 256, 0, stream>>>(1, xs_h, xs_l, wT_h,
                                                q_h, k_b, v_T, bias, mask, bsw);
        attn_kernel<<<dim3(32, 32), 256, 0, stream>>>(q_h, k_b, v_T, bsw, o_b);
    } else {
        u16* bsw = (u16*)(w + 32 * MB);   // aliases xs (dead after gemm) — sequential only
        gemm_qkv_bias<<<768, 256, 0, stream>>>(0, xs_h, xs_l, wT_h,
                                               q_h, k_b, v_T, bias, mask, bsw);
        gemm_qkv_bias<<<2048, 256, 0, stream>>>(2, xs_h, xs_l, wT_h,
                                                q_h, k_b, v_T, bias, mask, bsw);
        attn_kernel<<<dim3(32, 32), 256, 0, stream>>>(q_h, k_b, v_T, bsw, o_b);
    }
    gemm_out<<<dim3(16, 32), 256, 0, stream>>>(o_b, woT_h, bo, out);
}